// Round 3
// baseline (1014.634 us; speedup 1.0000x reference)
//
#include <hip/hip_runtime.h>

typedef unsigned short u16;
typedef unsigned int u32;
typedef float f32x4 __attribute__((ext_vector_type(4)));
typedef __bf16 bf16x8 __attribute__((ext_vector_type(8)));

#define NTOK 8192
#define HDIM 1024
#define FFDIM 4096
#define NEXP 8
#define CAP 1024

typedef const __attribute__((address_space(1))) void gvoid_t;
typedef __attribute__((address_space(3))) void lvoid_t;

__device__ __forceinline__ u16 f2bf(float f) {
  u32 u = __float_as_uint(f);
  u += 0x7fffu + ((u >> 16) & 1u);
  return (u16)(u >> 16);
}

// tanh-approx gelu (matches jax.nn.gelu approximate=True):
// gelu(x) = x * sigmoid(1.595769122 * (x + 0.044715 x^3))
__device__ __forceinline__ float gelu_f(float x) {
  float u = 1.5957691216057308f * (x + 0.044715f * x * x * x);
  return x / (1.0f + __expf(-u));
}

// ---------------- fp32 -> bf16 convert (vectorized) ----------------
__global__ __launch_bounds__(256) void convert_bf16(const float* __restrict__ src,
                                                    u16* __restrict__ dst,
                                                    long long n) {
  long long i = ((long long)blockIdx.x * 256 + threadIdx.x) * 8;
  if (i >= n) return;
  float4 f0 = *(const float4*)(src + i);
  float4 f1 = *(const float4*)(src + i + 4);
  union { u16 u[8]; uint4 v; } o;
  o.u[0] = f2bf(f0.x); o.u[1] = f2bf(f0.y); o.u[2] = f2bf(f0.z); o.u[3] = f2bf(f0.w);
  o.u[4] = f2bf(f1.x); o.u[5] = f2bf(f1.y); o.u[6] = f2bf(f1.z); o.u[7] = f2bf(f1.w);
  *(uint4*)(dst + i) = o.v;
}

// ---------------- transpose fp32 [R][C] -> bf16 [C][R] ----------------
__global__ __launch_bounds__(256) void transpose_f32_bf16(const float* __restrict__ src,
                                                          long long sBatch,
                                                          u16* __restrict__ dst,
                                                          long long dBatch,
                                                          int R, int C) {
  __shared__ float tile[32][33];
  int z = blockIdx.z;
  const float* s = src + (long long)z * sBatch;
  u16* d = dst + (long long)z * dBatch;
  int c0 = blockIdx.x * 32, r0 = blockIdx.y * 32;
  int tx = threadIdx.x, ty = threadIdx.y;  // (32, 8)
#pragma unroll
  for (int i = 0; i < 32; i += 8)
    tile[ty + i][tx] = s[(long long)(r0 + ty + i) * C + c0 + tx];
  __syncthreads();
#pragma unroll
  for (int i = 0; i < 32; i += 8)
    d[(long long)(c0 + ty + i) * R + r0 + tx] = f2bf(tile[tx][ty + i]);
}

// ---------------- gating: one wave per token, no atomics ----------------
__global__ __launch_bounds__(256) void gate_kernel(const float* __restrict__ x,
                                                   const float* __restrict__ wg,
                                                   const float* __restrict__ cw,
                                                   const float* __restrict__ cb,
                                                   int* __restrict__ idx1,
                                                   float* __restrict__ gate_val,
                                                   float* __restrict__ gates8,
                                                   float* __restrict__ coef) {
  const int wave = threadIdx.x >> 6, lane = threadIdx.x & 63;
  const int s = blockIdx.x * 4 + wave;
  const float* xr = x + (long long)s * HDIM;
  double p[10];
#pragma unroll
  for (int v = 0; v < 10; ++v) p[v] = 0.0;
#pragma unroll 4
  for (int i = 0; i < HDIM / 64; ++i) {
    int hh = i * 64 + lane;
    float xv = xr[hh];
    float4 w0 = *(const float4*)(wg + hh * 8);
    float4 w1 = *(const float4*)(wg + hh * 8 + 4);
    float2 c = *(const float2*)(cw + hh * 2);
    double xd = (double)xv;
    p[0] += xd * (double)w0.x; p[1] += xd * (double)w0.y;
    p[2] += xd * (double)w0.z; p[3] += xd * (double)w0.w;
    p[4] += xd * (double)w1.x; p[5] += xd * (double)w1.y;
    p[6] += xd * (double)w1.z; p[7] += xd * (double)w1.w;
    p[8] += xd * (double)c.x;  p[9] += xd * (double)c.y;
  }
#pragma unroll
  for (int v = 0; v < 10; ++v)
#pragma unroll
    for (int off = 32; off > 0; off >>= 1) p[v] += __shfl_down(p[v], off);
  if (lane == 0) {
    double mx = p[0]; int am = 0;
#pragma unroll
    for (int e = 1; e < 8; ++e)
      if (p[e] > mx) { mx = p[e]; am = e; }
    float g[8]; float sum = 0.f;
#pragma unroll
    for (int e = 0; e < 8; ++e) { g[e] = __expf((float)(p[e] - mx)); sum += g[e]; }
    float inv = 1.f / sum;
#pragma unroll
    for (int e = 0; e < 8; ++e) { g[e] *= inv; gates8[s * 8 + e] = g[e]; }
    idx1[s] = am;
    gate_val[s] = g[am];
    float c0 = (float)p[8] + cb[0], c1 = (float)p[9] + cb[1];
    float m2 = fmaxf(c0, c1);
    float e0 = __expf(c0 - m2), e1 = __expf(c1 - m2);
    float is = 1.f / (e0 + e1);
    coef[2 * s] = e0 * is;
    coef[2 * s + 1] = e1 * is;
  }
}

// ---------------- in-order cumsum scan: slot assignment + l_aux + counts ----------------
__global__ void scan_kernel(const int* __restrict__ idx1,
                            const float* __restrict__ gates8,
                            int* __restrict__ rowmap,     // [E][CAP] pre-filled -1
                            float* __restrict__ out_tail) // [l_aux, exp_counts x8]
{
  int lane = threadIdx.x;  // 64 threads, 1 block
  int cnt[8];
  float me[8];
#pragma unroll
  for (int e = 0; e < 8; ++e) { cnt[e] = 0; me[e] = 0.f; }
  unsigned long long below = (lane == 0) ? 0ull : ((~0ull) >> (64 - lane));
  for (int it = 0; it < NTOK / 64; ++it) {
    int tok = it * 64 + lane;
    int e = idx1[tok];
    const float* g = gates8 + tok * 8;
#pragma unroll
    for (int xx = 0; xx < 8; ++xx) me[xx] += g[xx];
#pragma unroll
    for (int xx = 0; xx < 8; ++xx) {
      unsigned long long m = __ballot(e == xx);
      if (e == xx) {
        int pos = cnt[xx] + __popcll(m & below);
        if (pos < CAP) rowmap[xx * CAP + pos] = tok;
      }
      cnt[xx] += __popcll(m);
    }
  }
#pragma unroll
  for (int xx = 0; xx < 8; ++xx)
#pragma unroll
    for (int off = 32; off > 0; off >>= 1) me[xx] += __shfl_down(me[xx], off);
  if (lane == 0) {
    float laux = 0.f;
#pragma unroll
    for (int e = 0; e < 8; ++e) {
      out_tail[1 + e] = (float)cnt[e];
      laux += (me[e] / (float)NTOK) * ((float)cnt[e] / (float)NTOK);
    }
    out_tail[0] = laux * (float)NEXP;
  }
}

// ---------------- 128x128 bf16 MFMA GEMM, global_load_lds staging ----------------
// A: [M][K] bf16 row-major (optionally row-indirect via amap), Bt: [N][K] bf16.
// mode 0: h = gelu(A@B) as bf16      mode 1: moe_acc[rmap[row]] = gate*val
// mode 2: out[row] = c0*moe_acc[row] + c1*val
__global__ __launch_bounds__(256) void gemm128(
    const u16* __restrict__ Aall, long long aBatch,
    const u16* __restrict__ Ball, long long bBatch,
    int M, int N, int K,
    const int* __restrict__ amapAll,  // nullptr or [Z][M] token-row map (-1 = empty)
    int mode,
    u16* __restrict__ hOut, long long hBatch,
    const int* __restrict__ rmapAll,
    const float* __restrict__ gate_val,
    float* __restrict__ moe_acc,
    const float* __restrict__ coef,
    float* __restrict__ outf) {
  const int z = blockIdx.z;
  const u16* A = Aall + (long long)z * aBatch;
  const u16* Bt = Ball + (long long)z * bBatch;

  const int tid = threadIdx.x;
  const int lane = tid & 63;
  const int wave = tid >> 6;
  const int wr = wave >> 1, wc = wave & 1;
  const int tileM = blockIdx.y * 128;
  const int tileN = blockIdx.x * 128;

  __shared__ __align__(16) u16 As[128 * 32];
  __shared__ __align__(16) u16 Bs[128 * 32];

  // async staging: wave w stages rows [32w, 32w+32) of A and Bt as two
  // 1024B chunks (16 rows x 64B). Lane i sources row chunkBase + (i>>2),
  // k-offset (i&3)*8; HW writes LDS at chunkDst + lane*16.
  const int sr0 = wave * 32 + (lane >> 2);  // chunk-0 source row (block-local)
  const int sr1 = sr0 + 16;                 // chunk-1 source row
  const int cS = (lane & 3) << 3;           // k element offset 0,8,16,24

  long long gaA0, gaA1;
  if (amapAll) {
    const int* amap = amapAll + (long long)z * M;
    int s0 = amap[tileM + sr0]; gaA0 = s0 < 0 ? 0 : s0;
    int s1 = amap[tileM + sr1]; gaA1 = s1 < 0 ? 0 : s1;
  } else {
    gaA0 = tileM + sr0;
    gaA1 = tileM + sr1;
  }

  const u16* aG0 = A + gaA0 * K + cS;
  const u16* aG1 = A + gaA1 * K + cS;
  const u16* bG0 = Bt + (long long)(tileN + sr0) * K + cS;
  const u16* bG1 = Bt + (long long)(tileN + sr1) * K + cS;

  // wave-uniform LDS chunk bases (elements): wave*1024, +512 for chunk 1
  u16* asD0 = As + wave * 1024;
  u16* asD1 = As + wave * 1024 + 512;
  u16* bsD0 = Bs + wave * 1024;
  u16* bsD1 = Bs + wave * 1024 + 512;

  f32x4 acc[4][4];
  const f32x4 fz = {0.f, 0.f, 0.f, 0.f};
#pragma unroll
  for (int i = 0; i < 4; ++i)
#pragma unroll
    for (int j = 0; j < 4; ++j) acc[i][j] = fz;

  const int k8 = (lane >> 4) << 3;  // quad * 8
  const int rlo = lane & 15;
  const u16* aRd = &As[(wr * 64 + rlo) * 32 + k8];
  const u16* bRd = &Bs[(wc * 64 + rlo) * 32 + k8];

  for (int kk = 0; kk < K; kk += 32) {
    __syncthreads();
    __builtin_amdgcn_global_load_lds((gvoid_t*)aG0, (lvoid_t*)asD0, 16, 0, 0);
    __builtin_amdgcn_global_load_lds((gvoid_t*)aG1, (lvoid_t*)asD1, 16, 0, 0);
    __builtin_amdgcn_global_load_lds((gvoid_t*)bG0, (lvoid_t*)bsD0, 16, 0, 0);
    __builtin_amdgcn_global_load_lds((gvoid_t*)bG1, (lvoid_t*)bsD1, 16, 0, 0);
    aG0 += 32; aG1 += 32; bG0 += 32; bG1 += 32;
    __syncthreads();
    bf16x8 af[4], bfr[4];
#pragma unroll
    for (int i = 0; i < 4; ++i) af[i] = *(const bf16x8*)(aRd + i * 16 * 32);
#pragma unroll
    for (int j = 0; j < 4; ++j) bfr[j] = *(const bf16x8*)(bRd + j * 16 * 32);
#pragma unroll
    for (int i = 0; i < 4; ++i)
#pragma unroll
      for (int j = 0; j < 4; ++j)
        acc[i][j] = __builtin_amdgcn_mfma_f32_16x16x32_bf16(af[i], bfr[j], acc[i][j], 0, 0, 0);
  }

  // epilogue: D row = (lane>>4)*4 + reg, col = lane&15 within each 16x16 tile
  const int qr = (lane >> 4) * 4;
  const int cc = lane & 15;
  if (mode == 0) {
    u16* hO = hOut + (long long)z * hBatch;
#pragma unroll
    for (int i = 0; i < 4; ++i) {
      int rbase = tileM + wr * 64 + i * 16 + qr;
#pragma unroll
      for (int j = 0; j < 4; ++j) {
        int col = tileN + wc * 64 + j * 16 + cc;
#pragma unroll
        for (int r = 0; r < 4; ++r)
          hO[(long long)(rbase + r) * N + col] = f2bf(gelu_f(acc[i][j][r]));
      }
    }
  } else if (mode == 1) {
    const int* rmap = rmapAll + (long long)z * M;
#pragma unroll
    for (int i = 0; i < 4; ++i) {
      int rbase = tileM + wr * 64 + i * 16 + qr;
#pragma unroll
      for (int j = 0; j < 4; ++j) {
        int col = tileN + wc * 64 + j * 16 + cc;
#pragma unroll
        for (int r = 0; r < 4; ++r) {
          int s = rmap[rbase + r];
          if (s >= 0) moe_acc[(long long)s * HDIM + col] = gate_val[s] * acc[i][j][r];
        }
      }
    }
  } else {
#pragma unroll
    for (int i = 0; i < 4; ++i) {
      int rbase = tileM + wr * 64 + i * 16 + qr;
#pragma unroll
      for (int j = 0; j < 4; ++j) {
        int col = tileN + wc * 64 + j * 16 + cc;
#pragma unroll
        for (int r = 0; r < 4; ++r) {
          int s = rbase + r;
          outf[(long long)s * HDIM + col] =
              coef[2 * s] * moe_acc[(long long)s * HDIM + col] + coef[2 * s + 1] * acc[i][j][r];
        }
      }
    }
  }
}

extern "C" void kernel_launch(void* const* d_in, const int* in_sizes, int n_in,
                              void* d_out, int out_size, void* d_ws, size_t ws_size,
                              hipStream_t stream) {
  (void)in_sizes; (void)n_in; (void)out_size; (void)ws_size;
  const float* x   = (const float*)d_in[0];
  const float* wg  = (const float*)d_in[1];
  const float* w1  = (const float*)d_in[2];
  const float* w2  = (const float*)d_in[3];
  const float* rw1 = (const float*)d_in[4];
  const float* rw2 = (const float*)d_in[5];
  const float* cw  = (const float*)d_in[6];
  const float* cb  = (const float*)d_in[7];
  float* out = (float*)d_out;

  char* ws = (char*)d_ws;
  constexpr size_t OFF_XB   = 0;
  constexpr size_t OFF_W1T  = OFF_XB  + (size_t)NTOK * HDIM * 2;        // 16.8 MB
  constexpr size_t OFF_W2T  = OFF_W1T + (size_t)NEXP * FFDIM * HDIM * 2; // +67 MB
  constexpr size_t OFF_H    = OFF_W2T + (size_t)NEXP * HDIM * FFDIM * 2; // +67 MB
  constexpr size_t OFF_MOE  = OFF_H   + (size_t)NEXP * CAP * FFDIM * 2;  // +67 MB
  constexpr size_t OFF_GATE = OFF_MOE + (size_t)NTOK * HDIM * 4;         // +33.5 MB
  constexpr size_t OFF_COEF = OFF_GATE + (size_t)NTOK * 4;
  constexpr size_t OFF_IDX  = OFF_COEF + (size_t)NTOK * 8;
  constexpr size_t OFF_RMAP = OFF_IDX + (size_t)NTOK * 4;
  constexpr size_t OFF_G8   = OFF_RMAP + (size_t)NEXP * CAP * 4;

  u16* xb        = (u16*)(ws + OFF_XB);
  u16* w1t       = (u16*)(ws + OFF_W1T);
  u16* w2t       = (u16*)(ws + OFF_W2T);
  u16* h         = (u16*)(ws + OFF_H);
  float* moe_acc = (float*)(ws + OFF_MOE);
  float* gate_v  = (float*)(ws + OFF_GATE);
  float* coef    = (float*)(ws + OFF_COEF);
  int* idx1      = (int*)(ws + OFF_IDX);
  int* rowmap    = (int*)(ws + OFF_RMAP);
  float* gates8  = (float*)(ws + OFF_G8);

  hipMemsetAsync(rowmap, 0xFF, (size_t)NEXP * CAP * 4, stream);
  hipMemsetAsync(moe_acc, 0, (size_t)NTOK * HDIM * 4, stream);

  convert_bf16<<<4096, 256, 0, stream>>>(x, xb, (long long)NTOK * HDIM);
  gate_kernel<<<NTOK / 4, 256, 0, stream>>>(x, wg, cw, cb, idx1, gate_v, gates8, coef);
  scan_kernel<<<1, 64, 0, stream>>>(idx1, gates8, rowmap, out + (size_t)NTOK * HDIM);

  // weight transposes: w1[e] [H][FF] -> w1t[e] [FF][H]; w2[e] [FF][H] -> w2t[e] [H][FF]
  transpose_f32_bf16<<<dim3(FFDIM / 32, HDIM / 32, NEXP), dim3(32, 8), 0, stream>>>(
      w1, (long long)HDIM * FFDIM, w1t, (long long)FFDIM * HDIM, HDIM, FFDIM);
  transpose_f32_bf16<<<dim3(HDIM / 32, FFDIM / 32, NEXP), dim3(32, 8), 0, stream>>>(
      w2, (long long)FFDIM * HDIM, w2t, (long long)HDIM * FFDIM, FFDIM, HDIM);

  // expert FFN1: h[e] = gelu(gather(xb, rowmap[e]) @ w1[e])   [CAP x FF]
  gemm128<<<dim3(FFDIM / 128, CAP / 128, NEXP), 256, 0, stream>>>(
      xb, 0, w1t, (long long)FFDIM * HDIM, CAP, FFDIM, HDIM,
      rowmap, 0, h, (long long)CAP * FFDIM, nullptr, nullptr, nullptr, nullptr, nullptr);
  // expert FFN2 + scatter: moe_acc[token] = gate * (h[e] @ w2[e])
  gemm128<<<dim3(HDIM / 128, CAP / 128, NEXP), 256, 0, stream>>>(
      h, (long long)CAP * FFDIM, w2t, (long long)HDIM * FFDIM, CAP, HDIM, FFDIM,
      nullptr, 1, nullptr, 0, rowmap, gate_v, moe_acc, nullptr, nullptr);

  // residual weights reuse the w1t/w2t regions
  transpose_f32_bf16<<<dim3(FFDIM / 32, HDIM / 32, 1), dim3(32, 8), 0, stream>>>(
      rw1, 0, w1t, 0, HDIM, FFDIM);
  transpose_f32_bf16<<<dim3(HDIM / 32, FFDIM / 32, 1), dim3(32, 8), 0, stream>>>(
      rw2, 0, w2t, 0, FFDIM, HDIM);

  // residual FFN1: h = gelu(xb @ res_w1)   [NTOK x FF]
  gemm128<<<dim3(FFDIM / 128, NTOK / 128, 1), 256, 0, stream>>>(
      xb, 0, w1t, 0, NTOK, FFDIM, HDIM,
      nullptr, 0, h, 0, nullptr, nullptr, nullptr, nullptr, nullptr);
  // residual FFN2 + final blend: out = c0*moe_acc + c1*(h @ res_w2)
  gemm128<<<dim3(HDIM / 128, NTOK / 128, 1), 256, 0, stream>>>(
      h, 0, w2t, 0, NTOK, HDIM, FFDIM,
      nullptr, 2, nullptr, 0, nullptr, nullptr, moe_acc, coef, out);
}

// Round 4
// 976.278 us; speedup vs baseline: 1.0393x; 1.0393x over previous
//
#include <hip/hip_runtime.h>

typedef unsigned short u16;
typedef unsigned int u32;
typedef float f32x4 __attribute__((ext_vector_type(4)));
typedef __bf16 bf16x8 __attribute__((ext_vector_type(8)));

#define NTOK 8192
#define HDIM 1024
#define FFDIM 4096
#define NEXP 8
#define CAP 1024

typedef const __attribute__((address_space(1))) void gvoid_t;
typedef __attribute__((address_space(3))) void lvoid_t;

__device__ __forceinline__ u16 f2bf(float f) {
  u32 u = __float_as_uint(f);
  u += 0x7fffu + ((u >> 16) & 1u);
  return (u16)(u >> 16);
}

// tanh-approx gelu (matches jax.nn.gelu approximate=True):
// gelu(x) = x * sigmoid(1.595769122 * (x + 0.044715 x^3))
__device__ __forceinline__ float gelu_f(float x) {
  float u = 1.5957691216057308f * (x + 0.044715f * x * x * x);
  return x / (1.0f + __expf(-u));
}

// ---------------- fp32 -> bf16 convert (vectorized) ----------------
__global__ __launch_bounds__(256) void convert_bf16(const float* __restrict__ src,
                                                    u16* __restrict__ dst,
                                                    long long n) {
  long long i = ((long long)blockIdx.x * 256 + threadIdx.x) * 8;
  if (i >= n) return;
  float4 f0 = *(const float4*)(src + i);
  float4 f1 = *(const float4*)(src + i + 4);
  union { u16 u[8]; uint4 v; } o;
  o.u[0] = f2bf(f0.x); o.u[1] = f2bf(f0.y); o.u[2] = f2bf(f0.z); o.u[3] = f2bf(f0.w);
  o.u[4] = f2bf(f1.x); o.u[5] = f2bf(f1.y); o.u[6] = f2bf(f1.z); o.u[7] = f2bf(f1.w);
  *(uint4*)(dst + i) = o.v;
}

// ---------------- transpose fp32 [R][C] -> bf16 [C][R] ----------------
__global__ __launch_bounds__(256) void transpose_f32_bf16(const float* __restrict__ src,
                                                          long long sBatch,
                                                          u16* __restrict__ dst,
                                                          long long dBatch,
                                                          int R, int C) {
  __shared__ float tile[32][33];
  int z = blockIdx.z;
  const float* s = src + (long long)z * sBatch;
  u16* d = dst + (long long)z * dBatch;
  int c0 = blockIdx.x * 32, r0 = blockIdx.y * 32;
  int tx = threadIdx.x, ty = threadIdx.y;  // (32, 8)
#pragma unroll
  for (int i = 0; i < 32; i += 8)
    tile[ty + i][tx] = s[(long long)(r0 + ty + i) * C + c0 + tx];
  __syncthreads();
#pragma unroll
  for (int i = 0; i < 32; i += 8)
    d[(long long)(c0 + ty + i) * R + r0 + tx] = f2bf(tile[tx][ty + i]);
}

// ---------------- gating: one wave per token, no atomics ----------------
__global__ __launch_bounds__(256) void gate_kernel(const float* __restrict__ x,
                                                   const float* __restrict__ wg,
                                                   const float* __restrict__ cw,
                                                   const float* __restrict__ cb,
                                                   int* __restrict__ idx1,
                                                   float* __restrict__ gate_val,
                                                   float* __restrict__ gates8,
                                                   float* __restrict__ coef) {
  const int wave = threadIdx.x >> 6, lane = threadIdx.x & 63;
  const int s = blockIdx.x * 4 + wave;
  const float* xr = x + (long long)s * HDIM;
  double p[10];
#pragma unroll
  for (int v = 0; v < 10; ++v) p[v] = 0.0;
#pragma unroll 4
  for (int i = 0; i < HDIM / 64; ++i) {
    int hh = i * 64 + lane;
    float xv = xr[hh];
    float4 w0 = *(const float4*)(wg + hh * 8);
    float4 w1 = *(const float4*)(wg + hh * 8 + 4);
    float2 c = *(const float2*)(cw + hh * 2);
    double xd = (double)xv;
    p[0] += xd * (double)w0.x; p[1] += xd * (double)w0.y;
    p[2] += xd * (double)w0.z; p[3] += xd * (double)w0.w;
    p[4] += xd * (double)w1.x; p[5] += xd * (double)w1.y;
    p[6] += xd * (double)w1.z; p[7] += xd * (double)w1.w;
    p[8] += xd * (double)c.x;  p[9] += xd * (double)c.y;
  }
#pragma unroll
  for (int v = 0; v < 10; ++v)
#pragma unroll
    for (int off = 32; off > 0; off >>= 1) p[v] += __shfl_down(p[v], off);
  if (lane == 0) {
    double mx = p[0]; int am = 0;
#pragma unroll
    for (int e = 1; e < 8; ++e)
      if (p[e] > mx) { mx = p[e]; am = e; }
    float g[8]; float sum = 0.f;
#pragma unroll
    for (int e = 0; e < 8; ++e) { g[e] = __expf((float)(p[e] - mx)); sum += g[e]; }
    float inv = 1.f / sum;
#pragma unroll
    for (int e = 0; e < 8; ++e) { g[e] *= inv; gates8[s * 8 + e] = g[e]; }
    idx1[s] = am;
    gate_val[s] = g[am];
    float c0 = (float)p[8] + cb[0], c1 = (float)p[9] + cb[1];
    float m2 = fmaxf(c0, c1);
    float e0 = __expf(c0 - m2), e1 = __expf(c1 - m2);
    float is = 1.f / (e0 + e1);
    coef[2 * s] = e0 * is;
    coef[2 * s + 1] = e1 * is;
  }
}

// ---------------- in-order cumsum scan: slot assignment + l_aux + counts ----------------
__global__ void scan_kernel(const int* __restrict__ idx1,
                            const float* __restrict__ gates8,
                            int* __restrict__ rowmap,     // [E][CAP] pre-filled -1
                            float* __restrict__ out_tail) // [l_aux, exp_counts x8]
{
  int lane = threadIdx.x;  // 64 threads, 1 block
  int cnt[8];
  float me[8];
#pragma unroll
  for (int e = 0; e < 8; ++e) { cnt[e] = 0; me[e] = 0.f; }
  unsigned long long below = (lane == 0) ? 0ull : ((~0ull) >> (64 - lane));
  for (int it = 0; it < NTOK / 64; ++it) {
    int tok = it * 64 + lane;
    int e = idx1[tok];
    const float* g = gates8 + tok * 8;
#pragma unroll
    for (int xx = 0; xx < 8; ++xx) me[xx] += g[xx];
#pragma unroll
    for (int xx = 0; xx < 8; ++xx) {
      unsigned long long m = __ballot(e == xx);
      if (e == xx) {
        int pos = cnt[xx] + __popcll(m & below);
        if (pos < CAP) rowmap[xx * CAP + pos] = tok;
      }
      cnt[xx] += __popcll(m);
    }
  }
#pragma unroll
  for (int xx = 0; xx < 8; ++xx)
#pragma unroll
    for (int off = 32; off > 0; off >>= 1) me[xx] += __shfl_down(me[xx], off);
  if (lane == 0) {
    float laux = 0.f;
#pragma unroll
    for (int e = 0; e < 8; ++e) {
      out_tail[1 + e] = (float)cnt[e];
      laux += (me[e] / (float)NTOK) * ((float)cnt[e] / (float)NTOK);
    }
    out_tail[0] = laux * (float)NEXP;
  }
}

// ---------------- 128x128 bf16 MFMA GEMM ----------------
// global_load_lds staging, double-buffered LDS, XOR-swizzled k-chunks.
// A: [M][K] bf16 row-major (optionally row-indirect via amap), Bt: [N][K] bf16.
// mode 0: h = gelu(A@B) as bf16      mode 1: moe_acc[rmap[row]] = gate*val
// mode 2: out[row] = c0*moe_acc[row] + c1*val
__global__ __launch_bounds__(256) void gemm128(
    const u16* __restrict__ Aall, long long aBatch,
    const u16* __restrict__ Ball, long long bBatch,
    int M, int N, int K,
    const int* __restrict__ amapAll,  // nullptr or [Z][M] token-row map (-1 = empty)
    int mode,
    u16* __restrict__ hOut, long long hBatch,
    const int* __restrict__ rmapAll,
    const float* __restrict__ gate_val,
    float* __restrict__ moe_acc,
    const float* __restrict__ coef,
    float* __restrict__ outf) {
  const int z = blockIdx.z;
  const u16* A = Aall + (long long)z * aBatch;
  const u16* Bt = Ball + (long long)z * bBatch;

  const int tid = threadIdx.x;
  const int lane = tid & 63;
  const int wave = tid >> 6;
  const int wr = wave >> 1, wc = wave & 1;
  const int tileM = blockIdx.y * 128;
  const int tileN = blockIdx.x * 128;

  // double-buffered tiles: [buf][128 rows][32 k]
  __shared__ __align__(16) u16 As[2][128 * 32];
  __shared__ __align__(16) u16 Bs[2][128 * 32];

  // async staging: wave w stages rows [32w, 32w+32) of A and Bt as two
  // 1024B chunks (16 rows x 64B). LDS addr is fixed (chunkBase + lane*16),
  // so the k-chunk swizzle is applied to the GLOBAL source per lane:
  //   LDS slot (row, c) holds global k-chunk c ^ ((row>>1)&3).
  const int sr0 = wave * 32 + (lane >> 2);  // chunk-0 source row (block-local)
  const int sr1 = sr0 + 16;                 // chunk-1 source row
  const int cS = (((lane & 3) ^ ((lane >> 3) & 3)) << 3);  // swizzled k offset

  long long gaA0, gaA1;
  if (amapAll) {
    const int* amap = amapAll + (long long)z * M;
    int s0 = amap[tileM + sr0]; gaA0 = s0 < 0 ? 0 : s0;
    int s1 = amap[tileM + sr1]; gaA1 = s1 < 0 ? 0 : s1;
  } else {
    gaA0 = tileM + sr0;
    gaA1 = tileM + sr1;
  }

  const u16* aG0 = A + gaA0 * K + cS;
  const u16* aG1 = A + gaA1 * K + cS;
  const u16* bG0 = Bt + (long long)(tileN + sr0) * K + cS;
  const u16* bG1 = Bt + (long long)(tileN + sr1) * K + cS;

  const int ldsChunk = wave * 1024;  // wave-uniform element base within a buffer

  f32x4 acc[4][4];
  const f32x4 fz = {0.f, 0.f, 0.f, 0.f};
#pragma unroll
  for (int i = 0; i < 4; ++i)
#pragma unroll
    for (int j = 0; j < 4; ++j) acc[i][j] = fz;

  // fragment-read offsets (swizzled to match): row = wr*64 + i*16 + rlo,
  // k-quad kq = lane>>4; element = row*32 + ((kq ^ ((rlo>>1)&3))<<3).
  const int rlo = lane & 15;
  const int kq = lane >> 4;
  const int swzR = (rlo >> 1) & 3;
  const int aOff = (wr * 64 + rlo) * 32 + ((kq ^ swzR) << 3);
  const int bOff = (wc * 64 + rlo) * 32 + ((kq ^ swzR) << 3);

  // prologue: stage tile 0 into buffer 0
  __builtin_amdgcn_global_load_lds((gvoid_t*)aG0, (lvoid_t*)&As[0][ldsChunk], 16, 0, 0);
  __builtin_amdgcn_global_load_lds((gvoid_t*)aG1, (lvoid_t*)&As[0][ldsChunk + 512], 16, 0, 0);
  __builtin_amdgcn_global_load_lds((gvoid_t*)bG0, (lvoid_t*)&Bs[0][ldsChunk], 16, 0, 0);
  __builtin_amdgcn_global_load_lds((gvoid_t*)bG1, (lvoid_t*)&Bs[0][ldsChunk + 512], 16, 0, 0);
  aG0 += 32; aG1 += 32; bG0 += 32; bG1 += 32;

  int cur = 0;
  for (int kk = 0; kk < K; kk += 32) {
    __syncthreads();  // drains vmcnt: buf[cur] staged; prior reads of buf[cur^1] retired
    if (kk + 32 < K) {
      int nxt = cur ^ 1;
      __builtin_amdgcn_global_load_lds((gvoid_t*)aG0, (lvoid_t*)&As[nxt][ldsChunk], 16, 0, 0);
      __builtin_amdgcn_global_load_lds((gvoid_t*)aG1, (lvoid_t*)&As[nxt][ldsChunk + 512], 16, 0, 0);
      __builtin_amdgcn_global_load_lds((gvoid_t*)bG0, (lvoid_t*)&Bs[nxt][ldsChunk], 16, 0, 0);
      __builtin_amdgcn_global_load_lds((gvoid_t*)bG1, (lvoid_t*)&Bs[nxt][ldsChunk + 512], 16, 0, 0);
      aG0 += 32; aG1 += 32; bG0 += 32; bG1 += 32;
    }
    bf16x8 af[4], bfr[4];
#pragma unroll
    for (int i = 0; i < 4; ++i) af[i] = *(const bf16x8*)(&As[cur][aOff + i * 16 * 32]);
#pragma unroll
    for (int j = 0; j < 4; ++j) bfr[j] = *(const bf16x8*)(&Bs[cur][bOff + j * 16 * 32]);
#pragma unroll
    for (int i = 0; i < 4; ++i)
#pragma unroll
      for (int j = 0; j < 4; ++j)
        acc[i][j] = __builtin_amdgcn_mfma_f32_16x16x32_bf16(af[i], bfr[j], acc[i][j], 0, 0, 0);
    cur ^= 1;
  }

  // epilogue: D row = (lane>>4)*4 + reg, col = lane&15 within each 16x16 tile
  const int qr = (lane >> 4) * 4;
  const int cc = lane & 15;
  if (mode == 0) {
    u16* hO = hOut + (long long)z * hBatch;
#pragma unroll
    for (int i = 0; i < 4; ++i) {
      int rbase = tileM + wr * 64 + i * 16 + qr;
#pragma unroll
      for (int j = 0; j < 4; ++j) {
        int col = tileN + wc * 64 + j * 16 + cc;
#pragma unroll
        for (int r = 0; r < 4; ++r)
          hO[(long long)(rbase + r) * N + col] = f2bf(gelu_f(acc[i][j][r]));
      }
    }
  } else if (mode == 1) {
    const int* rmap = rmapAll + (long long)z * M;
#pragma unroll
    for (int i = 0; i < 4; ++i) {
      int rbase = tileM + wr * 64 + i * 16 + qr;
#pragma unroll
      for (int j = 0; j < 4; ++j) {
        int col = tileN + wc * 64 + j * 16 + cc;
#pragma unroll
        for (int r = 0; r < 4; ++r) {
          int s = rmap[rbase + r];
          if (s >= 0) moe_acc[(long long)s * HDIM + col] = gate_val[s] * acc[i][j][r];
        }
      }
    }
  } else {
#pragma unroll
    for (int i = 0; i < 4; ++i) {
      int rbase = tileM + wr * 64 + i * 16 + qr;
#pragma unroll
      for (int j = 0; j < 4; ++j) {
        int col = tileN + wc * 64 + j * 16 + cc;
#pragma unroll
        for (int r = 0; r < 4; ++r) {
          int s = rbase + r;
          outf[(long long)s * HDIM + col] =
              coef[2 * s] * moe_acc[(long long)s * HDIM + col] + coef[2 * s + 1] * acc[i][j][r];
        }
      }
    }
  }
}

extern "C" void kernel_launch(void* const* d_in, const int* in_sizes, int n_in,
                              void* d_out, int out_size, void* d_ws, size_t ws_size,
                              hipStream_t stream) {
  (void)in_sizes; (void)n_in; (void)out_size; (void)ws_size;
  const float* x   = (const float*)d_in[0];
  const float* wg  = (const float*)d_in[1];
  const float* w1  = (const float*)d_in[2];
  const float* w2  = (const float*)d_in[3];
  const float* rw1 = (const float*)d_in[4];
  const float* rw2 = (const float*)d_in[5];
  const float* cw  = (const float*)d_in[6];
  const float* cb  = (const float*)d_in[7];
  float* out = (float*)d_out;

  char* ws = (char*)d_ws;
  constexpr size_t OFF_XB   = 0;
  constexpr size_t OFF_W1T  = OFF_XB  + (size_t)NTOK * HDIM * 2;        // 16.8 MB
  constexpr size_t OFF_W2T  = OFF_W1T + (size_t)NEXP * FFDIM * HDIM * 2; // +67 MB
  constexpr size_t OFF_H    = OFF_W2T + (size_t)NEXP * HDIM * FFDIM * 2; // +67 MB
  constexpr size_t OFF_MOE  = OFF_H   + (size_t)NEXP * CAP * FFDIM * 2;  // +67 MB
  constexpr size_t OFF_GATE = OFF_MOE + (size_t)NTOK * HDIM * 4;         // +33.5 MB
  constexpr size_t OFF_COEF = OFF_GATE + (size_t)NTOK * 4;
  constexpr size_t OFF_IDX  = OFF_COEF + (size_t)NTOK * 8;
  constexpr size_t OFF_RMAP = OFF_IDX + (size_t)NTOK * 4;
  constexpr size_t OFF_G8   = OFF_RMAP + (size_t)NEXP * CAP * 4;

  u16* xb        = (u16*)(ws + OFF_XB);
  u16* w1t       = (u16*)(ws + OFF_W1T);
  u16* w2t       = (u16*)(ws + OFF_W2T);
  u16* h         = (u16*)(ws + OFF_H);
  float* moe_acc = (float*)(ws + OFF_MOE);
  float* gate_v  = (float*)(ws + OFF_GATE);
  float* coef    = (float*)(ws + OFF_COEF);
  int* idx1      = (int*)(ws + OFF_IDX);
  int* rowmap    = (int*)(ws + OFF_RMAP);
  float* gates8  = (float*)(ws + OFF_G8);

  hipMemsetAsync(rowmap, 0xFF, (size_t)NEXP * CAP * 4, stream);
  hipMemsetAsync(moe_acc, 0, (size_t)NTOK * HDIM * 4, stream);

  convert_bf16<<<4096, 256, 0, stream>>>(x, xb, (long long)NTOK * HDIM);
  gate_kernel<<<NTOK / 4, 256, 0, stream>>>(x, wg, cw, cb, idx1, gate_v, gates8, coef);
  scan_kernel<<<1, 64, 0, stream>>>(idx1, gates8, rowmap, out + (size_t)NTOK * HDIM);

  // weight transposes: w1[e] [H][FF] -> w1t[e] [FF][H]; w2[e] [FF][H] -> w2t[e] [H][FF]
  transpose_f32_bf16<<<dim3(FFDIM / 32, HDIM / 32, NEXP), dim3(32, 8), 0, stream>>>(
      w1, (long long)HDIM * FFDIM, w1t, (long long)FFDIM * HDIM, HDIM, FFDIM);
  transpose_f32_bf16<<<dim3(HDIM / 32, FFDIM / 32, NEXP), dim3(32, 8), 0, stream>>>(
      w2, (long long)FFDIM * HDIM, w2t, (long long)HDIM * FFDIM, FFDIM, HDIM);

  // expert FFN1: h[e] = gelu(gather(xb, rowmap[e]) @ w1[e])   [CAP x FF]
  gemm128<<<dim3(FFDIM / 128, CAP / 128, NEXP), 256, 0, stream>>>(
      xb, 0, w1t, (long long)FFDIM * HDIM, CAP, FFDIM, HDIM,
      rowmap, 0, h, (long long)CAP * FFDIM, nullptr, nullptr, nullptr, nullptr, nullptr);
  // expert FFN2 + scatter: moe_acc[token] = gate * (h[e] @ w2[e])
  gemm128<<<dim3(HDIM / 128, CAP / 128, NEXP), 256, 0, stream>>>(
      h, (long long)CAP * FFDIM, w2t, (long long)HDIM * FFDIM, CAP, HDIM, FFDIM,
      nullptr, 1, nullptr, 0, rowmap, gate_v, moe_acc, nullptr, nullptr);

  // residual weights reuse the w1t/w2t regions
  transpose_f32_bf16<<<dim3(FFDIM / 32, HDIM / 32, 1), dim3(32, 8), 0, stream>>>(
      rw1, 0, w1t, 0, HDIM, FFDIM);
  transpose_f32_bf16<<<dim3(HDIM / 32, FFDIM / 32, 1), dim3(32, 8), 0, stream>>>(
      rw2, 0, w2t, 0, FFDIM, HDIM);

  // residual FFN1: h = gelu(xb @ res_w1)   [NTOK x FF]
  gemm128<<<dim3(FFDIM / 128, NTOK / 128, 1), 256, 0, stream>>>(
      xb, 0, w1t, 0, NTOK, FFDIM, HDIM,
      nullptr, 0, h, 0, nullptr, nullptr, nullptr, nullptr, nullptr);
  // residual FFN2 + final blend: out = c0*moe_acc + c1*(h @ res_w2)
  gemm128<<<dim3(HDIM / 128, NTOK / 128, 1), 256, 0, stream>>>(
      h, 0, w2t, 0, NTOK, HDIM, FFDIM,
      nullptr, 2, nullptr, 0, nullptr, nullptr, moe_acc, coef, out);
}

// Round 5
// 897.984 us; speedup vs baseline: 1.1299x; 1.0872x over previous
//
#include <hip/hip_runtime.h>

typedef unsigned short u16;
typedef unsigned int u32;
typedef float f32x4 __attribute__((ext_vector_type(4)));
typedef __bf16 bf16x8 __attribute__((ext_vector_type(8)));

#define NTOK 8192
#define HDIM 1024
#define FFDIM 4096
#define NEXP 8
#define CAP 1024

typedef const __attribute__((address_space(1))) void gvoid_t;
typedef __attribute__((address_space(3))) void lvoid_t;

__device__ __forceinline__ u16 f2bf(float f) {
  u32 u = __float_as_uint(f);
  u += 0x7fffu + ((u >> 16) & 1u);
  return (u16)(u >> 16);
}

// tanh-approx gelu (matches jax.nn.gelu approximate=True):
// gelu(x) = x * sigmoid(1.595769122 * (x + 0.044715 x^3))
__device__ __forceinline__ float gelu_f(float x) {
  float u = 1.5957691216057308f * (x + 0.044715f * x * x * x);
  return x / (1.0f + __expf(-u));
}

// ---------------- fp32 -> bf16 convert (vectorized) ----------------
__global__ __launch_bounds__(256) void convert_bf16(const float* __restrict__ src,
                                                    u16* __restrict__ dst,
                                                    long long n) {
  long long i = ((long long)blockIdx.x * 256 + threadIdx.x) * 8;
  if (i >= n) return;
  float4 f0 = *(const float4*)(src + i);
  float4 f1 = *(const float4*)(src + i + 4);
  union { u16 u[8]; uint4 v; } o;
  o.u[0] = f2bf(f0.x); o.u[1] = f2bf(f0.y); o.u[2] = f2bf(f0.z); o.u[3] = f2bf(f0.w);
  o.u[4] = f2bf(f1.x); o.u[5] = f2bf(f1.y); o.u[6] = f2bf(f1.z); o.u[7] = f2bf(f1.w);
  *(uint4*)(dst + i) = o.v;
}

// ---------------- transpose fp32 [R][C] -> bf16 [C][R] ----------------
__global__ __launch_bounds__(256) void transpose_f32_bf16(const float* __restrict__ src,
                                                          long long sBatch,
                                                          u16* __restrict__ dst,
                                                          long long dBatch,
                                                          int R, int C) {
  __shared__ float tile[32][33];
  int z = blockIdx.z;
  const float* s = src + (long long)z * sBatch;
  u16* d = dst + (long long)z * dBatch;
  int c0 = blockIdx.x * 32, r0 = blockIdx.y * 32;
  int tx = threadIdx.x, ty = threadIdx.y;  // (32, 8)
#pragma unroll
  for (int i = 0; i < 32; i += 8)
    tile[ty + i][tx] = s[(long long)(r0 + ty + i) * C + c0 + tx];
  __syncthreads();
#pragma unroll
  for (int i = 0; i < 32; i += 8)
    d[(long long)(c0 + ty + i) * R + r0 + tx] = f2bf(tile[tx][ty + i]);
}

// ---------------- gating: one wave per token, no atomics ----------------
__global__ __launch_bounds__(256) void gate_kernel(const float* __restrict__ x,
                                                   const float* __restrict__ wg,
                                                   const float* __restrict__ cw,
                                                   const float* __restrict__ cb,
                                                   int* __restrict__ idx1,
                                                   float* __restrict__ gate_val,
                                                   float* __restrict__ gates8,
                                                   float* __restrict__ coef) {
  const int wave = threadIdx.x >> 6, lane = threadIdx.x & 63;
  const int s = blockIdx.x * 4 + wave;
  const float* xr = x + (long long)s * HDIM;
  double p[10];
#pragma unroll
  for (int v = 0; v < 10; ++v) p[v] = 0.0;
#pragma unroll 4
  for (int i = 0; i < HDIM / 64; ++i) {
    int hh = i * 64 + lane;
    float xv = xr[hh];
    float4 w0 = *(const float4*)(wg + hh * 8);
    float4 w1 = *(const float4*)(wg + hh * 8 + 4);
    float2 c = *(const float2*)(cw + hh * 2);
    double xd = (double)xv;
    p[0] += xd * (double)w0.x; p[1] += xd * (double)w0.y;
    p[2] += xd * (double)w0.z; p[3] += xd * (double)w0.w;
    p[4] += xd * (double)w1.x; p[5] += xd * (double)w1.y;
    p[6] += xd * (double)w1.z; p[7] += xd * (double)w1.w;
    p[8] += xd * (double)c.x;  p[9] += xd * (double)c.y;
  }
#pragma unroll
  for (int v = 0; v < 10; ++v)
#pragma unroll
    for (int off = 32; off > 0; off >>= 1) p[v] += __shfl_down(p[v], off);
  if (lane == 0) {
    double mx = p[0]; int am = 0;
#pragma unroll
    for (int e = 1; e < 8; ++e)
      if (p[e] > mx) { mx = p[e]; am = e; }
    float g[8]; float sum = 0.f;
#pragma unroll
    for (int e = 0; e < 8; ++e) { g[e] = __expf((float)(p[e] - mx)); sum += g[e]; }
    float inv = 1.f / sum;
#pragma unroll
    for (int e = 0; e < 8; ++e) { g[e] *= inv; gates8[s * 8 + e] = g[e]; }
    idx1[s] = am;
    gate_val[s] = g[am];
    float c0 = (float)p[8] + cb[0], c1 = (float)p[9] + cb[1];
    float m2 = fmaxf(c0, c1);
    float e0 = __expf(c0 - m2), e1 = __expf(c1 - m2);
    float is = 1.f / (e0 + e1);
    coef[2 * s] = e0 * is;
    coef[2 * s + 1] = e1 * is;
  }
}

// ---------------- in-order cumsum scan: slot assignment + l_aux + counts ----------------
// software-prefetched: next iteration's idx1/gates8 loads issue before the
// current iteration's dependent ballot chain.
__global__ void scan_kernel(const int* __restrict__ idx1,
                            const float* __restrict__ gates8,
                            int* __restrict__ rowmap,     // [E][CAP] pre-filled -1
                            float* __restrict__ out_tail) // [l_aux, exp_counts x8]
{
  int lane = threadIdx.x;  // 64 threads, 1 block
  int cnt[8];
  float me[8];
#pragma unroll
  for (int e = 0; e < 8; ++e) { cnt[e] = 0; me[e] = 0.f; }
  unsigned long long below = (lane == 0) ? 0ull : ((~0ull) >> (64 - lane));
  int eN = idx1[lane];
  float4 gN0 = *(const float4*)(gates8 + lane * 8);
  float4 gN1 = *(const float4*)(gates8 + lane * 8 + 4);
  for (int it = 0; it < NTOK / 64; ++it) {
    int tok = it * 64 + lane;
    int e = eN;
    float4 g0 = gN0, g1 = gN1;
    if (it + 1 < NTOK / 64) {
      eN = idx1[tok + 64];
      gN0 = *(const float4*)(gates8 + (tok + 64) * 8);
      gN1 = *(const float4*)(gates8 + (tok + 64) * 8 + 4);
    }
    me[0] += g0.x; me[1] += g0.y; me[2] += g0.z; me[3] += g0.w;
    me[4] += g1.x; me[5] += g1.y; me[6] += g1.z; me[7] += g1.w;
#pragma unroll
    for (int xx = 0; xx < 8; ++xx) {
      unsigned long long m = __ballot(e == xx);
      if (e == xx) {
        int pos = cnt[xx] + __popcll(m & below);
        if (pos < CAP) rowmap[xx * CAP + pos] = tok;
      }
      cnt[xx] += __popcll(m);
    }
  }
#pragma unroll
  for (int xx = 0; xx < 8; ++xx)
#pragma unroll
    for (int off = 32; off > 0; off >>= 1) me[xx] += __shfl_down(me[xx], off);
  if (lane == 0) {
    float laux = 0.f;
#pragma unroll
    for (int e = 0; e < 8; ++e) {
      out_tail[1 + e] = (float)cnt[e];
      laux += (me[e] / (float)NTOK) * ((float)cnt[e] / (float)NTOK);
    }
    out_tail[0] = laux * (float)NEXP;
  }
}

// ---------------- 128x128 bf16 MFMA GEMM, BK=64 ----------------
// global_load_lds staging (single buffer, 32 KiB), XOR-swizzled 16B k-chunks:
// LDS slot s of row r holds global k-chunk s^(r&7)  (rows are 64 elem = 128 B,
// 8 chunks of 16 B). 32 MFMAs + 16 ds_read_b128 per barrier per wave.
// A: [M][K] bf16 row-major (optionally row-indirect via amap), Bt: [N][K] bf16.
// mode 0: h = gelu(A@B) as bf16      mode 1: moe_acc[rmap[row]] = gate*val
// mode 2: out[row] = c0*moe_acc[row] + c1*val
__global__ __launch_bounds__(256) void gemm128(
    const u16* __restrict__ Aall, long long aBatch,
    const u16* __restrict__ Ball, long long bBatch,
    int M, int N, int K,
    const int* __restrict__ amapAll,  // nullptr or [Z][M] token-row map (-1 = empty)
    int mode,
    u16* __restrict__ hOut, long long hBatch,
    const int* __restrict__ rmapAll,
    const float* __restrict__ gate_val,
    float* __restrict__ moe_acc,
    const float* __restrict__ coef,
    float* __restrict__ outf) {
  const int z = blockIdx.z;
  const u16* A = Aall + (long long)z * aBatch;
  const u16* Bt = Ball + (long long)z * bBatch;

  const int tid = threadIdx.x;
  const int lane = tid & 63;
  const int wave = tid >> 6;
  const int wr = wave >> 1, wc = wave & 1;
  const int tileM = blockIdx.y * 128;
  const int tileN = blockIdx.x * 128;

  // single-buffered tiles: 128 rows x 64 k, row stride 64 elem (128 B)
  __shared__ __align__(16) u16 As[128 * 64];
  __shared__ __align__(16) u16 Bs[128 * 64];

  // staging: wave w stages rows [32w, 32w+32) of A and Bt as 4 chunks of
  // 8 rows x 128 B. Lane i: chunk-local row = i>>3, LDS slot = i&7; the slot
  // holds global k-chunk (i&7)^(i>>3)  (row&7 == i>>3 since bases are %8==0).
  const int lrow = lane >> 3;                    // 0..7
  const int gk = (((lane & 7) ^ lrow) << 3);     // swizzled global k offset

  int sr[4];
#pragma unroll
  for (int c = 0; c < 4; ++c) sr[c] = wave * 32 + c * 8 + lrow;

  long long gaA[4];
  if (amapAll) {
    const int* amap = amapAll + (long long)z * M;
#pragma unroll
    for (int c = 0; c < 4; ++c) {
      int s0 = amap[tileM + sr[c]];
      gaA[c] = s0 < 0 ? 0 : s0;
    }
  } else {
#pragma unroll
    for (int c = 0; c < 4; ++c) gaA[c] = tileM + sr[c];
  }

  const u16* aG[4];
  const u16* bG[4];
#pragma unroll
  for (int c = 0; c < 4; ++c) {
    aG[c] = A + gaA[c] * K + gk;
    bG[c] = Bt + (long long)(tileN + sr[c]) * K + gk;
  }

  f32x4 acc[4][4];
  const f32x4 fz = {0.f, 0.f, 0.f, 0.f};
#pragma unroll
  for (int i = 0; i < 4; ++i)
#pragma unroll
    for (int j = 0; j < 4; ++j) acc[i][j] = fz;

  // fragment-read offsets: row = 64*wq + i*16 + rlo, k = sub*32 + kq*8 + j
  // swizzled chunk = (sub*4 + kq) ^ (rlo & 7)
  const int rlo = lane & 15;
  const int kq = lane >> 4;  // 0..3
  const int sw = rlo & 7;
  const int ks0 = (kq ^ sw) << 3;
  const int ks1 = ((4 | kq) ^ sw) << 3;
  int aRow[4], bRow[4];
#pragma unroll
  for (int i = 0; i < 4; ++i) {
    aRow[i] = (wr * 64 + i * 16 + rlo) * 64;
    bRow[i] = (wc * 64 + i * 16 + rlo) * 64;
  }

  for (int kk = 0; kk < K; kk += 64) {
    __syncthreads();
#pragma unroll
    for (int c = 0; c < 4; ++c) {
      __builtin_amdgcn_global_load_lds((gvoid_t*)aG[c],
          (lvoid_t*)&As[(wave * 32 + c * 8) * 64], 16, 0, 0);
      __builtin_amdgcn_global_load_lds((gvoid_t*)bG[c],
          (lvoid_t*)&Bs[(wave * 32 + c * 8) * 64], 16, 0, 0);
      aG[c] += 64;
      bG[c] += 64;
    }
    __syncthreads();
#pragma unroll
    for (int sub = 0; sub < 2; ++sub) {
      const int ks = sub ? ks1 : ks0;
      bf16x8 af[4], bfr[4];
#pragma unroll
      for (int i = 0; i < 4; ++i) af[i] = *(const bf16x8*)(&As[aRow[i] + ks]);
#pragma unroll
      for (int j = 0; j < 4; ++j) bfr[j] = *(const bf16x8*)(&Bs[bRow[j] + ks]);
#pragma unroll
      for (int i = 0; i < 4; ++i)
#pragma unroll
        for (int j = 0; j < 4; ++j)
          acc[i][j] = __builtin_amdgcn_mfma_f32_16x16x32_bf16(af[i], bfr[j], acc[i][j], 0, 0, 0);
    }
  }

  // epilogue: D row = (lane>>4)*4 + reg, col = lane&15 within each 16x16 tile
  const int qr = (lane >> 4) * 4;
  const int cc = lane & 15;
  if (mode == 0) {
    u16* hO = hOut + (long long)z * hBatch;
#pragma unroll
    for (int i = 0; i < 4; ++i) {
      int rbase = tileM + wr * 64 + i * 16 + qr;
#pragma unroll
      for (int j = 0; j < 4; ++j) {
        int col = tileN + wc * 64 + j * 16 + cc;
#pragma unroll
        for (int r = 0; r < 4; ++r)
          hO[(long long)(rbase + r) * N + col] = f2bf(gelu_f(acc[i][j][r]));
      }
    }
  } else if (mode == 1) {
    const int* rmap = rmapAll + (long long)z * M;
#pragma unroll
    for (int i = 0; i < 4; ++i) {
      int rbase = tileM + wr * 64 + i * 16 + qr;
#pragma unroll
      for (int j = 0; j < 4; ++j) {
        int col = tileN + wc * 64 + j * 16 + cc;
#pragma unroll
        for (int r = 0; r < 4; ++r) {
          int s = rmap[rbase + r];
          if (s >= 0) moe_acc[(long long)s * HDIM + col] = gate_val[s] * acc[i][j][r];
        }
      }
    }
  } else {
#pragma unroll
    for (int i = 0; i < 4; ++i) {
      int rbase = tileM + wr * 64 + i * 16 + qr;
#pragma unroll
      for (int j = 0; j < 4; ++j) {
        int col = tileN + wc * 64 + j * 16 + cc;
#pragma unroll
        for (int r = 0; r < 4; ++r) {
          int s = rbase + r;
          outf[(long long)s * HDIM + col] =
              coef[2 * s] * moe_acc[(long long)s * HDIM + col] + coef[2 * s + 1] * acc[i][j][r];
        }
      }
    }
  }
}

extern "C" void kernel_launch(void* const* d_in, const int* in_sizes, int n_in,
                              void* d_out, int out_size, void* d_ws, size_t ws_size,
                              hipStream_t stream) {
  (void)in_sizes; (void)n_in; (void)out_size; (void)ws_size;
  const float* x   = (const float*)d_in[0];
  const float* wg  = (const float*)d_in[1];
  const float* w1  = (const float*)d_in[2];
  const float* w2  = (const float*)d_in[3];
  const float* rw1 = (const float*)d_in[4];
  const float* rw2 = (const float*)d_in[5];
  const float* cw  = (const float*)d_in[6];
  const float* cb  = (const float*)d_in[7];
  float* out = (float*)d_out;

  char* ws = (char*)d_ws;
  constexpr size_t OFF_XB   = 0;
  constexpr size_t OFF_W1T  = OFF_XB  + (size_t)NTOK * HDIM * 2;        // 16.8 MB
  constexpr size_t OFF_W2T  = OFF_W1T + (size_t)NEXP * FFDIM * HDIM * 2; // +67 MB
  constexpr size_t OFF_H    = OFF_W2T + (size_t)NEXP * HDIM * FFDIM * 2; // +67 MB
  constexpr size_t OFF_MOE  = OFF_H   + (size_t)NEXP * CAP * FFDIM * 2;  // +67 MB
  constexpr size_t OFF_GATE = OFF_MOE + (size_t)NTOK * HDIM * 4;         // +33.5 MB
  constexpr size_t OFF_COEF = OFF_GATE + (size_t)NTOK * 4;
  constexpr size_t OFF_IDX  = OFF_COEF + (size_t)NTOK * 8;
  constexpr size_t OFF_RMAP = OFF_IDX + (size_t)NTOK * 4;
  constexpr size_t OFF_G8   = OFF_RMAP + (size_t)NEXP * CAP * 4;

  u16* xb        = (u16*)(ws + OFF_XB);
  u16* w1t       = (u16*)(ws + OFF_W1T);
  u16* w2t       = (u16*)(ws + OFF_W2T);
  u16* h         = (u16*)(ws + OFF_H);
  float* moe_acc = (float*)(ws + OFF_MOE);
  float* gate_v  = (float*)(ws + OFF_GATE);
  float* coef    = (float*)(ws + OFF_COEF);
  int* idx1      = (int*)(ws + OFF_IDX);
  int* rowmap    = (int*)(ws + OFF_RMAP);
  float* gates8  = (float*)(ws + OFF_G8);

  hipMemsetAsync(rowmap, 0xFF, (size_t)NEXP * CAP * 4, stream);
  hipMemsetAsync(moe_acc, 0, (size_t)NTOK * HDIM * 4, stream);

  convert_bf16<<<4096, 256, 0, stream>>>(x, xb, (long long)NTOK * HDIM);
  gate_kernel<<<NTOK / 4, 256, 0, stream>>>(x, wg, cw, cb, idx1, gate_v, gates8, coef);
  scan_kernel<<<1, 64, 0, stream>>>(idx1, gates8, rowmap, out + (size_t)NTOK * HDIM);

  // weight transposes: w1[e] [H][FF] -> w1t[e] [FF][H]; w2[e] [FF][H] -> w2t[e] [H][FF]
  transpose_f32_bf16<<<dim3(FFDIM / 32, HDIM / 32, NEXP), dim3(32, 8), 0, stream>>>(
      w1, (long long)HDIM * FFDIM, w1t, (long long)FFDIM * HDIM, HDIM, FFDIM);
  transpose_f32_bf16<<<dim3(HDIM / 32, FFDIM / 32, NEXP), dim3(32, 8), 0, stream>>>(
      w2, (long long)FFDIM * HDIM, w2t, (long long)HDIM * FFDIM, FFDIM, HDIM);

  // expert FFN1: h[e] = gelu(gather(xb, rowmap[e]) @ w1[e])   [CAP x FF]
  gemm128<<<dim3(FFDIM / 128, CAP / 128, NEXP), 256, 0, stream>>>(
      xb, 0, w1t, (long long)FFDIM * HDIM, CAP, FFDIM, HDIM,
      rowmap, 0, h, (long long)CAP * FFDIM, nullptr, nullptr, nullptr, nullptr, nullptr);
  // expert FFN2 + scatter: moe_acc[token] = gate * (h[e] @ w2[e])
  gemm128<<<dim3(HDIM / 128, CAP / 128, NEXP), 256, 0, stream>>>(
      h, (long long)CAP * FFDIM, w2t, (long long)HDIM * FFDIM, CAP, HDIM, FFDIM,
      nullptr, 1, nullptr, 0, rowmap, gate_v, moe_acc, nullptr, nullptr);

  // residual weights reuse the w1t/w2t regions
  transpose_f32_bf16<<<dim3(FFDIM / 32, HDIM / 32, 1), dim3(32, 8), 0, stream>>>(
      rw1, 0, w1t, 0, HDIM, FFDIM);
  transpose_f32_bf16<<<dim3(HDIM / 32, FFDIM / 32, 1), dim3(32, 8), 0, stream>>>(
      rw2, 0, w2t, 0, FFDIM, HDIM);

  // residual FFN1: h = gelu(xb @ res_w1)   [NTOK x FF]
  gemm128<<<dim3(FFDIM / 128, NTOK / 128, 1), 256, 0, stream>>>(
      xb, 0, w1t, 0, NTOK, FFDIM, HDIM,
      nullptr, 0, h, 0, nullptr, nullptr, nullptr, nullptr, nullptr);
  // residual FFN2 + final blend: out = c0*moe_acc + c1*(h @ res_w2)
  gemm128<<<dim3(HDIM / 128, NTOK / 128, 1), 256, 0, stream>>>(
      h, 0, w2t, 0, NTOK, HDIM, FFDIM,
      nullptr, 2, nullptr, 0, nullptr, nullptr, moe_acc, coef, out);
}